// Round 1
// baseline (3292.361 us; speedup 1.0000x reference)
//
#include <hip/hip_runtime.h>
#include <stdint.h>

// ---------------------------------------------------------------------------
// Seq2seq decoder: Luong attention + 2-layer LSTM, B=64, T=48, S=48, E=512,
// H=1024. Strategy:
//   - precompute encW = enc @ W_l (so scores = h1 . encW, no per-step q GEMM)
//   - precompute emb-part of layer0 gates for all T (preG) + biases
//   - per step: attn kernel, layer0 GEMM+cell (fused), layer1 GEMM+cell
//   - all matmuls bf16 MFMA (16x16x32), f32 accum / state / softmax / cell
// ---------------------------------------------------------------------------

using short8 = __attribute__((ext_vector_type(8))) short;
using f32x4  = __attribute__((ext_vector_type(4))) float;
typedef unsigned short u16;

#define B_  64
#define T_  48
#define S_  48
#define H_  1024
#define E_  512

__device__ __forceinline__ float bf2f(u16 u) {
    union { unsigned int i; float f; } v; v.i = ((unsigned int)u) << 16; return v.f;
}
__device__ __forceinline__ u16 f2bf(float f) {
    union { float f; unsigned int i; } v; v.f = f;
    unsigned int r = v.i + 0x7fff + ((v.i >> 16) & 1);   // RNE
    return (u16)(r >> 16);
}
__device__ __forceinline__ float sigm(float x) { return 1.f / (1.f + __expf(-x)); }

// ---------------- trivial converters ----------------

// dst[r*dld + doff + c] = bf16(src[r*sld + soff + c]), cols = 1<<colshift
__global__ void cast_copy(u16* __restrict__ dst, int dld, int doff,
                          const float* __restrict__ src, int sld, int soff,
                          int rows, int colshift) {
    int cols = 1 << colshift;
    int total = rows << colshift;
    for (int i = blockIdx.x * blockDim.x + threadIdx.x; i < total;
         i += gridDim.x * blockDim.x) {
        int r = i >> colshift, c = i & (cols - 1);
        dst[(size_t)r * dld + doff + c] = f2bf(src[(size_t)r * sld + soff + c]);
    }
}

// WlT[i][j] = W_l[j][i]  (1024x1024)
__global__ void transpose_cast(u16* __restrict__ dst, const float* __restrict__ src) {
    int idx = blockIdx.x * blockDim.x + threadIdx.x;   // 1M threads exactly
    int r = idx >> 10, c = idx & 1023;
    dst[idx] = f2bf(src[(size_t)c * 1024 + r]);
}

// embA[(t*64+b)][e] = bf16(embedding[tgt[b][t]][e])
__global__ void embed_gather(u16* __restrict__ embA, const float* __restrict__ emb,
                             const int* __restrict__ tgt) {
    int row = blockIdx.x;              // t*64 + b
    int t = row >> 6, b = row & 63;
    int id = tgt[b * T_ + t];
    const float* s = emb + (size_t)id * E_;
    u16* d = embA + (size_t)row * E_;
    for (int e = threadIdx.x; e < E_; e += blockDim.x) d[e] = f2bf(s[e]);
}

// sbias[r] = sum_i b_l[i] * enc[r][i]
__global__ void sbias_kernel(float* __restrict__ sbias, const float* __restrict__ enc,
                             const float* __restrict__ b_l) {
    int r = blockIdx.x, lane = threadIdx.x;
    const float* e = enc + (size_t)r * H_;
    float acc = 0.f;
    for (int k = lane; k < H_; k += 64) acc += b_l[k] * e[k];
    for (int o = 32; o; o >>= 1) acc += __shfl_xor(acc, o);
    if (lane == 0) sbias[r] = acc;
}

// init hidden/cell state buffers
__global__ void init_state(u16* __restrict__ xa0, u16* __restrict__ xa1,
                           float* __restrict__ c0b, float* __restrict__ c1b,
                           const float* __restrict__ h0, const float* __restrict__ c0) {
    int i = blockIdx.x * blockDim.x + threadIdx.x;   // 131072 exactly
    int l = i >> 16, rem = i & 65535, b = rem >> 10, c = rem & 1023;
    u16 hb = f2bf(h0[i]);
    float cv = c0[i];
    if (l == 0) { xa0[b * 2048 + 1024 + c] = hb; c0b[rem] = cv; }
    else        { xa1[b * 2048 + 1024 + c] = hb; c1b[rem] = cv; }
}

// ---------------- generic bf16 MFMA GEMM: D[M][N] = A[M][K] * W[N][K]^T ------
// grid = (N/64, M/64), block 256 (4 waves, each wave owns 16 N-cols)
__global__ __launch_bounds__(256) void gemm_nt(
    const u16* __restrict__ A, const u16* __restrict__ W, u16* __restrict__ D,
    const float* __restrict__ bias1, const float* __restrict__ bias2,
    int N, int Kd)
{
    int tid = threadIdx.x, w = tid >> 6, lane = tid & 63;
    int half = lane >> 4, q = lane & 15;
    int n0 = blockIdx.x * 64 + w * 16;
    int m0 = blockIdx.y * 64;
    const u16* wp = W + (size_t)(n0 + q) * Kd + half * 8;
    const u16* ap = A + (size_t)(m0 + q) * Kd + half * 8;
    f32x4 acc[4] = {};
    for (int k0 = 0; k0 < Kd; k0 += 32) {
        short8 bf = *(const short8*)(wp + k0);
#pragma unroll
        for (int m = 0; m < 4; ++m) {
            short8 af = *(const short8*)(ap + (size_t)m * 16 * Kd + k0);
            acc[m] = __builtin_amdgcn_mfma_f32_16x16x32_bf16(af, bf, acc[m], 0, 0, 0);
        }
    }
    float badd = bias1 ? (bias1[n0 + q] + bias2[n0 + q]) : 0.f;
#pragma unroll
    for (int m = 0; m < 4; ++m)
#pragma unroll
        for (int r = 0; r < 4; ++r)
            D[(size_t)(m0 + m * 16 + half * 4 + r) * N + n0 + q] = f2bf(acc[m][r] + badd);
}

// ---------------- attention (one block per batch element) -------------------
__global__ __launch_bounds__(256) void attn_kernel(
    const u16* __restrict__ xa1cur,   // h1(t-1) bf16 at [b*2048 + 1024 + i]
    const u16* __restrict__ encW,     // [B*S][H] bf16
    const u16* __restrict__ encB,     // [B*S][H] bf16
    const float* __restrict__ sbias,  // [B*S]
    const unsigned char* __restrict__ mask,
    u16* __restrict__ ctxDst)         // XA0 cur base: write [b*2048 + j]
{
    int b = blockIdx.x, tid = threadIdx.x;
    __shared__ float h1s[H_];
    __shared__ float partS[S_][4];
    __shared__ float pr[S_];
    for (int i = tid; i < H_; i += 256) h1s[i] = bf2f(xa1cur[b * 2048 + 1024 + i]);
    __syncthreads();
    if (tid < S_ * 4) {
        int s = tid >> 2, kg = tid & 3;
        const u16* ep = encW + ((size_t)b * S_ + s) * H_ + kg * 256;
        const float* hp = h1s + kg * 256;
        float acc = 0.f;
        for (int k = 0; k < 256; k += 8) {
            union { short8 v; u16 u[8]; } x;
            x.v = *(const short8*)(ep + k);
#pragma unroll
            for (int e = 0; e < 8; ++e) acc += hp[k + e] * bf2f(x.u[e]);
        }
        partS[s][kg] = acc;
    }
    __syncthreads();
    if (tid < 64) {
        float v = -3.0e38f;
        if (tid < S_) {
            v = partS[tid][0] + partS[tid][1] + partS[tid][2] + partS[tid][3]
                + sbias[b * S_ + tid];
            if (mask[b * S_ + tid]) v = -3.0e38f;
        }
        float mx = v;
        for (int o = 32; o; o >>= 1) mx = fmaxf(mx, __shfl_xor(mx, o));
        float e = (tid < S_) ? __expf(v - mx) : 0.f;
        float sum = e;
        for (int o = 32; o; o >>= 1) sum += __shfl_xor(sum, o);
        if (tid < S_) pr[tid] = e / sum;
    }
    __syncthreads();
#pragma unroll
    for (int j = 0; j < 4; ++j) {
        int col = tid + j * 256;
        float acc = 0.f;
        for (int s = 0; s < S_; ++s)
            acc += pr[s] * bf2f(encB[((size_t)b * S_ + s) * H_ + col]);
        ctxDst[b * 2048 + col] = f2bf(acc);
    }
}

// ---------------- fused LSTM layer: gates GEMM (K=2048) + cell --------------
// grid = 256 blocks (4 h-cols each), block = 256 (4 waves split K in 512-chunks)
__global__ __launch_bounds__(256) void lstm_gemm_cell(
    const u16* __restrict__ A,       // [64][2048] bf16 ([ctx|h0] or [h0'|h1])
    const u16* __restrict__ W,       // [4096][2048] bf16 ([W_ihX | W_hhX])
    const u16* __restrict__ preG,    // layer0: &preG[t*64*4096] (has biases), else null
    const float* __restrict__ bia, const float* __restrict__ bib,  // layer1 biases
    float* __restrict__ cbuf,        // [64][1024] f32 cell state (in-place)
    u16* __restrict__ hA,            // bf16 h dst #1 (index b*2048 + col)
    u16* __restrict__ hB,            // bf16 h dst #2 or null
    float* __restrict__ outBase,     // f32 outputs base (layer1) or null
    int t, int last,
    float* __restrict__ hnOut, float* __restrict__ cnOut)
{
    __shared__ float part[4][64][16];
    int tid = threadIdx.x, w = tid >> 6, lane = tid & 63;
    int half = lane >> 4, q = lane & 15;
    int c0 = blockIdx.x * 4;                       // h-col base (4 cols/block)
    int row = (q >> 2) * 1024 + c0 + (q & 3);      // gate row for this lane
    int kb = w * 512 + half * 8;
    const u16* wp = W + (size_t)row * 2048 + kb;
    const u16* ap = A + kb;
    f32x4 acc[4] = {};
#pragma unroll
    for (int k0 = 0; k0 < 512; k0 += 32) {
        short8 bf = *(const short8*)(wp + k0);
#pragma unroll
        for (int m = 0; m < 4; ++m) {
            short8 af = *(const short8*)(ap + (m * 16 + q) * 2048 + k0);
            acc[m] = __builtin_amdgcn_mfma_f32_16x16x32_bf16(af, bf, acc[m], 0, 0, 0);
        }
    }
#pragma unroll
    for (int m = 0; m < 4; ++m)
#pragma unroll
        for (int r = 0; r < 4; ++r)
            part[w][m * 16 + half * 4 + r][q] = acc[m][r];
    __syncthreads();
#pragma unroll
    for (int j = 0; j < 4; ++j) {
        int idx = tid + j * 256;               // 1024 (b, q) pairs
        int bb = idx >> 4, qq = idx & 15;
        float v = part[0][bb][qq] + part[1][bb][qq] + part[2][bb][qq] + part[3][bb][qq];
        int gr = (qq >> 2) * 1024 + c0 + (qq & 3);
        if (preG) v += bf2f(preG[(size_t)bb * 4096 + gr]);
        if (bia)  v += bia[gr] + bib[gr];
        part[0][bb][qq] = v;                   // each (bb,qq) touched by one thread
    }
    __syncthreads();
    // cell: 256 threads, one (b, col) each
    int bb = tid >> 2, jj = tid & 3, ccol = c0 + jj;
    float ig = part[0][bb][jj],     fg = part[0][bb][4 + jj];
    float gg = part[0][bb][8 + jj], og = part[0][bb][12 + jj];
    float cp = cbuf[bb * 1024 + ccol];
    float cnew = sigm(fg) * cp + sigm(ig) * tanhf(gg);
    float hnew = sigm(og) * tanhf(cnew);
    cbuf[bb * 1024 + ccol] = cnew;
    u16 hb16 = f2bf(hnew);
    hA[bb * 2048 + ccol] = hb16;
    if (hB) hB[bb * 2048 + ccol] = hb16;
    if (outBase) outBase[((size_t)bb * T_ + t) * H_ + ccol] = hnew;
    if (last) { hnOut[bb * 1024 + ccol] = hnew; cnOut[bb * 1024 + ccol] = cnew; }
}

// ---------------------------------------------------------------------------

extern "C" void kernel_launch(void* const* d_in, const int* in_sizes, int n_in,
                              void* d_out, int out_size, void* d_ws, size_t ws_size,
                              hipStream_t stream) {
    const int*   tgt      = (const int*)d_in[0];
    const float* h0       = (const float*)d_in[1];
    const float* c0in     = (const float*)d_in[2];
    const float* enc      = (const float*)d_in[3];
    const unsigned char* mask = (const unsigned char*)d_in[4];
    const float* embedding= (const float*)d_in[5];
    const float* W_l      = (const float*)d_in[6];
    const float* b_l      = (const float*)d_in[7];
    const float* W_ih0    = (const float*)d_in[8];
    const float* W_hh0    = (const float*)d_in[9];
    const float* b_ih0    = (const float*)d_in[10];
    const float* b_hh0    = (const float*)d_in[11];
    const float* W_ih1    = (const float*)d_in[12];
    const float* W_hh1    = (const float*)d_in[13];
    const float* b_ih1    = (const float*)d_in[14];
    const float* b_hh1    = (const float*)d_in[15];
    float* out = (float*)d_out;

    char* ws = (char*)d_ws;
    u16* W0emb = (u16*)ws;               ws += (size_t)4096 * 512 * 2;
    u16* W0cat = (u16*)ws;               ws += (size_t)4096 * 2048 * 2;
    u16* W1cat = (u16*)ws;               ws += (size_t)4096 * 2048 * 2;
    u16* WlT   = (u16*)ws;               ws += (size_t)1024 * 1024 * 2;
    u16* embA  = (u16*)ws;               ws += (size_t)3072 * 512 * 2;
    u16* encB  = (u16*)ws;               ws += (size_t)3072 * 1024 * 2;
    u16* encWb = (u16*)ws;               ws += (size_t)3072 * 1024 * 2;
    float* sbias = (float*)ws;           ws += (size_t)3072 * 4;
    u16* preG  = (u16*)ws;               ws += (size_t)3072 * 4096 * 2;
    u16* XA0   = (u16*)ws;               ws += (size_t)2 * 64 * 2048 * 2;
    u16* XA1   = (u16*)ws;               ws += (size_t)2 * 64 * 2048 * 2;
    float* c0buf = (float*)ws;           ws += (size_t)64 * 1024 * 4;
    float* c1buf = (float*)ws;           ws += (size_t)64 * 1024 * 4;

    // ---- one-time (per launch) setup ----
    cast_copy<<<2048, 256, 0, stream>>>(W0emb, 512, 0,    W_ih0, 1536, 0,   4096, 9);
    cast_copy<<<2048, 256, 0, stream>>>(W0cat, 2048, 0,   W_ih0, 1536, 512, 4096, 10);
    cast_copy<<<2048, 256, 0, stream>>>(W0cat, 2048, 1024, W_hh0, 1024, 0,  4096, 10);
    cast_copy<<<2048, 256, 0, stream>>>(W1cat, 2048, 0,   W_ih1, 1024, 0,   4096, 10);
    cast_copy<<<2048, 256, 0, stream>>>(W1cat, 2048, 1024, W_hh1, 1024, 0,  4096, 10);
    cast_copy<<<2048, 256, 0, stream>>>(encB, 1024, 0,    enc,   1024, 0,   3072, 10);
    transpose_cast<<<4096, 256, 0, stream>>>(WlT, W_l);
    embed_gather<<<3072, 256, 0, stream>>>(embA, embedding, tgt);
    init_state<<<512, 256, 0, stream>>>(XA0, XA1, c0buf, c1buf, h0, c0in);
    sbias_kernel<<<3072, 64, 0, stream>>>(sbias, enc, b_l);
    // preG[t*64+b][:] = embA @ W0emb^T + b_ih0 + b_hh0
    gemm_nt<<<dim3(64, 48), 256, 0, stream>>>(embA, W0emb, preG, b_ih0, b_hh0, 4096, 512);
    // encW = encB @ W_l  (via WlT rows)
    gemm_nt<<<dim3(16, 48), 256, 0, stream>>>(encB, WlT, encWb, nullptr, nullptr, 1024, 1024);

    float* hn0 = out + 3145728;           // hn[0]
    float* hn1 = hn0 + 65536;             // hn[1]
    float* cn0 = out + 3276800;           // cn[0]
    float* cn1 = cn0 + 65536;             // cn[1]

    for (int t = 0; t < T_; ++t) {
        int p = t & 1, pn = p ^ 1, last = (t == T_ - 1);
        u16* xa0c = XA0 + (size_t)p  * 131072;
        u16* xa0n = XA0 + (size_t)pn * 131072;
        u16* xa1c = XA1 + (size_t)p  * 131072;
        u16* xa1n = XA1 + (size_t)pn * 131072;

        // attention: ctx -> XA0cur[:, 0:1024]
        attn_kernel<<<64, 256, 0, stream>>>(xa1c, encWb, encB, sbias, mask, xa0c);
        // layer 0: gates from [ctx|h0] + preG, cell -> h0' (XA1cur[:,0:1024],
        // XA0next[:,1024:2048]); c0buf updated
        lstm_gemm_cell<<<256, 256, 0, stream>>>(
            xa0c, W0cat, preG + (size_t)t * 64 * 4096, nullptr, nullptr,
            c0buf, xa1c, xa0n + 1024, nullptr, t, last, hn0, cn0);
        // layer 1: gates from [h0'|h1] + biases, cell -> h1'
        // (XA1next[:,1024:2048]) + outputs[b][t][:]
        lstm_gemm_cell<<<256, 256, 0, stream>>>(
            xa1c, W1cat, nullptr, b_ih1, b_hh1,
            c1buf, xa1n + 1024, nullptr, out, t, last, hn1, cn1);
    }
    (void)in_sizes; (void)n_in; (void)out_size; (void)ws_size; (void)mask;
}

// Round 2
// 2033.520 us; speedup vs baseline: 1.6190x; 1.6190x over previous
//
#include <hip/hip_runtime.h>
#include <stdint.h>

// ---------------------------------------------------------------------------
// Seq2seq decoder: Luong attention + 2-layer LSTM, B=64, T=48, S=48, E=512,
// H=1024. Round 2: reuse-oriented per-step GEMM (lstm_fused), vectorized
// attention ctx phase, better setup GEMM (gemm64).
// ---------------------------------------------------------------------------

using short8 = __attribute__((ext_vector_type(8))) short;
using f32x4  = __attribute__((ext_vector_type(4))) float;
typedef unsigned short u16;

#define B_  64
#define T_  48
#define S_  48
#define H_  1024
#define E_  512

__device__ __forceinline__ float bf2f(u16 u) {
    union { unsigned int i; float f; } v; v.i = ((unsigned int)u) << 16; return v.f;
}
__device__ __forceinline__ u16 f2bf(float f) {
    union { float f; unsigned int i; } v; v.f = f;
    unsigned int r = v.i + 0x7fff + ((v.i >> 16) & 1);   // RNE
    return (u16)(r >> 16);
}
__device__ __forceinline__ float sigm(float x) { return 1.f / (1.f + __expf(-x)); }

// ---------------- trivial converters ----------------

__global__ void cast_copy(u16* __restrict__ dst, int dld, int doff,
                          const float* __restrict__ src, int sld, int soff,
                          int rows, int colshift) {
    int cols = 1 << colshift;
    int total = rows << colshift;
    for (int i = blockIdx.x * blockDim.x + threadIdx.x; i < total;
         i += gridDim.x * blockDim.x) {
        int r = i >> colshift, c = i & (cols - 1);
        dst[(size_t)r * dld + doff + c] = f2bf(src[(size_t)r * sld + soff + c]);
    }
}

// WlT[i][j] = W_l[j][i]  (1024x1024)
__global__ void transpose_cast(u16* __restrict__ dst, const float* __restrict__ src) {
    int idx = blockIdx.x * blockDim.x + threadIdx.x;   // 1M threads exactly
    int r = idx >> 10, c = idx & 1023;
    dst[idx] = f2bf(src[(size_t)c * 1024 + r]);
}

// embA[(t*64+b)][e] = bf16(embedding[tgt[b][t]][e])
__global__ void embed_gather(u16* __restrict__ embA, const float* __restrict__ emb,
                             const int* __restrict__ tgt) {
    int row = blockIdx.x;              // t*64 + b
    int t = row >> 6, b = row & 63;
    int id = tgt[b * T_ + t];
    const float* s = emb + (size_t)id * E_;
    u16* d = embA + (size_t)row * E_;
    for (int e = threadIdx.x; e < E_; e += blockDim.x) d[e] = f2bf(s[e]);
}

// sbias[r] = sum_i b_l[i] * enc[r][i]
__global__ void sbias_kernel(float* __restrict__ sbias, const float* __restrict__ enc,
                             const float* __restrict__ b_l) {
    int r = blockIdx.x, lane = threadIdx.x;
    const float* e = enc + (size_t)r * H_;
    float acc = 0.f;
    for (int k = lane; k < H_; k += 64) acc += b_l[k] * e[k];
    for (int o = 32; o; o >>= 1) acc += __shfl_xor(acc, o);
    if (lane == 0) sbias[r] = acc;
}

// init hidden/cell state buffers
__global__ void init_state(u16* __restrict__ xa0, u16* __restrict__ xa1,
                           float* __restrict__ c0b, float* __restrict__ c1b,
                           const float* __restrict__ h0, const float* __restrict__ c0) {
    int i = blockIdx.x * blockDim.x + threadIdx.x;   // 131072 exactly
    int l = i >> 16, rem = i & 65535, b = rem >> 10, c = rem & 1023;
    u16 hb = f2bf(h0[i]);
    float cv = c0[i];
    if (l == 0) { xa0[b * 2048 + 1024 + c] = hb; c0b[rem] = cv; }
    else        { xa1[b * 2048 + 1024 + c] = hb; c1b[rem] = cv; }
}

// ---------------- setup GEMM: D[M][N] = A[M][K] * W[N][K]^T + bias ----------
// grid = (N/64, M/64), block 256 = 4 waves, waves split K 4 ways.
__global__ __launch_bounds__(256) void gemm64(
    const u16* __restrict__ A, const u16* __restrict__ W, u16* __restrict__ D,
    const float* __restrict__ bias1, const float* __restrict__ bias2,
    int N, int Kd)
{
    __shared__ float part[4][64][64];        // 64 KB
    int tid = threadIdx.x, w = tid >> 6, lane = tid & 63;
    int half = lane >> 4, q = lane & 15;
    int n0 = blockIdx.x * 64, m0 = blockIdx.y * 64;
    int ks = Kd >> 2;                        // K-slice per wave
    int kb = w * ks + half * 8;
    const u16* ap = A + (size_t)(m0 + q) * Kd + kb;
    const u16* wp = W + (size_t)(n0 + q) * Kd + kb;
    f32x4 acc[4][4] = {};
    for (int k0 = 0; k0 < ks; k0 += 32) {
        short8 bf[4], af[4];
#pragma unroll
        for (int n = 0; n < 4; ++n) bf[n] = *(const short8*)(wp + (size_t)n * 16 * Kd + k0);
#pragma unroll
        for (int m = 0; m < 4; ++m) af[m] = *(const short8*)(ap + (size_t)m * 16 * Kd + k0);
#pragma unroll
        for (int m = 0; m < 4; ++m)
#pragma unroll
            for (int n = 0; n < 4; ++n)
                acc[m][n] = __builtin_amdgcn_mfma_f32_16x16x32_bf16(af[m], bf[n], acc[m][n], 0, 0, 0);
    }
#pragma unroll
    for (int m = 0; m < 4; ++m)
#pragma unroll
        for (int n = 0; n < 4; ++n)
#pragma unroll
            for (int r = 0; r < 4; ++r)
                part[w][m * 16 + half * 4 + r][n * 16 + q] = acc[m][n][r];
    __syncthreads();
#pragma unroll
    for (int k = 0; k < 16; ++k) {
        int o = tid + k * 256;               // 4096 outputs
        int row = o >> 6, col = o & 63;
        float v = part[0][row][col] + part[1][row][col]
                + part[2][row][col] + part[3][row][col];
        if (bias1) v += bias1[n0 + col] + bias2[n0 + col];
        D[(size_t)(m0 + row) * N + n0 + col] = f2bf(v);
    }
}

// ---------------- attention (one block per batch element) -------------------
__global__ __launch_bounds__(256) void attn_kernel(
    const u16* __restrict__ xa1cur,   // h1(t-1) bf16 at [b*2048 + 1024 + i]
    const u16* __restrict__ encW,     // [B*S][H] bf16 (enc @ W_l)
    const u16* __restrict__ encB,     // [B*S][H] bf16
    const float* __restrict__ sbias,  // [B*S]
    const unsigned char* __restrict__ mask,
    u16* __restrict__ ctxDst)         // XA0 cur base: write [b*2048 + j]
{
    int b = blockIdx.x, tid = threadIdx.x;
    __shared__ float h1s[H_];
    __shared__ float partS[S_][4];
    __shared__ float pr[S_];
    __shared__ float cpart[2][H_];
    for (int i = tid; i < H_; i += 256) h1s[i] = bf2f(xa1cur[b * 2048 + 1024 + i]);
    __syncthreads();
    if (tid < S_ * 4) {
        int s = tid >> 2, kg = tid & 3;
        const u16* ep = encW + ((size_t)b * S_ + s) * H_ + kg * 256;
        const float* hp = h1s + kg * 256;
        float acc = 0.f;
        for (int k = 0; k < 256; k += 8) {
            union { short8 v; u16 u[8]; } x;
            x.v = *(const short8*)(ep + k);
#pragma unroll
            for (int e = 0; e < 8; ++e) acc += hp[k + e] * bf2f(x.u[e]);
        }
        partS[s][kg] = acc;
    }
    __syncthreads();
    if (tid < 64) {
        float v = -3.0e38f;
        if (tid < S_) {
            v = partS[tid][0] + partS[tid][1] + partS[tid][2] + partS[tid][3]
                + sbias[b * S_ + tid];
            if (mask[b * S_ + tid]) v = -3.0e38f;
        }
        float mx = v;
        for (int o = 32; o; o >>= 1) mx = fmaxf(mx, __shfl_xor(mx, o));
        float e = (tid < S_) ? __expf(v - mx) : 0.f;
        float sum = e;
        for (int o = 32; o; o >>= 1) sum += __shfl_xor(sum, o);
        if (tid < S_) pr[tid] = e / sum;
    }
    __syncthreads();
    // ctx: thread (cg, sh): cols cg*8..+7, s in [sh*24, sh*24+24)
    {
        int cg = tid & 127, sh = tid >> 7;
        const u16* ebase = encB + ((size_t)b * S_ + sh * 24) * H_ + cg * 8;
        float a8[8] = {};
        for (int s = 0; s < 24; ++s) {
            float p = pr[sh * 24 + s];
            union { short8 v; u16 u[8]; } x;
            x.v = *(const short8*)(ebase + (size_t)s * H_);
#pragma unroll
            for (int e = 0; e < 8; ++e) a8[e] += p * bf2f(x.u[e]);
        }
#pragma unroll
        for (int e = 0; e < 8; ++e) cpart[sh][cg * 8 + e] = a8[e];
    }
    __syncthreads();
#pragma unroll
    for (int k = 0; k < 4; ++k) {
        int col = tid + k * 256;
        ctxDst[b * 2048 + col] = f2bf(cpart[0][col] + cpart[1][col]);
    }
}

// ---------------- fused LSTM layer: gates GEMM (K=2048) + cell --------------
// grid = 128 blocks (8 h-cols each = 32 gate rows), block 512 = 8 waves
// splitting K=2048 in 256-wide slices. LDS reduce + fused cell epilogue.
__global__ __launch_bounds__(512) void lstm_fused(
    const u16* __restrict__ A,       // [64][2048] bf16 ([ctx|h0] or [h0'|h1])
    const u16* __restrict__ W,       // [4096][2048] bf16 ([W_ihX | W_hhX])
    const u16* __restrict__ preG,    // layer0: &preG[t*64*4096] (has biases), else null
    const float* __restrict__ bia, const float* __restrict__ bib,  // layer1 biases
    float* __restrict__ cbuf,        // [64][1024] f32 cell state (in-place)
    u16* __restrict__ hA,            // bf16 h dst #1 (index b*2048 + col)
    u16* __restrict__ hB,            // bf16 h dst #2 or null
    float* __restrict__ outBase,     // f32 outputs base (layer1) or null
    int t, int last,
    float* __restrict__ hnOut, float* __restrict__ cnOut)
{
    __shared__ float part[8][64][32];        // 64 KB
    int tid = threadIdx.x, w = tid >> 6, lane = tid & 63;
    int half = lane >> 4, q = lane & 15;
    int c0 = blockIdx.x * 8;                 // h-col base (8 cols/block)
    int kb = w * 256 + half * 8;             // this wave's K-slice
    int row0 = (q >> 3) * 1024 + c0 + (q & 7);   // gates 0/1 (i,f)
    const u16* wp0 = W + (size_t)row0 * 2048 + kb;
    const u16* wp1 = wp0 + (size_t)2048 * 2048;  // gates 2/3 (g,o)
    const u16* ap  = A + (size_t)q * 2048 + kb;
    f32x4 acc[4][2] = {};
#pragma unroll
    for (int k0 = 0; k0 < 256; k0 += 32) {
        short8 b0 = *(const short8*)(wp0 + k0);
        short8 b1 = *(const short8*)(wp1 + k0);
#pragma unroll
        for (int m = 0; m < 4; ++m) {
            short8 af = *(const short8*)(ap + (size_t)m * 16 * 2048 + k0);
            acc[m][0] = __builtin_amdgcn_mfma_f32_16x16x32_bf16(af, b0, acc[m][0], 0, 0, 0);
            acc[m][1] = __builtin_amdgcn_mfma_f32_16x16x32_bf16(af, b1, acc[m][1], 0, 0, 0);
        }
    }
#pragma unroll
    for (int m = 0; m < 4; ++m)
#pragma unroll
        for (int n = 0; n < 2; ++n)
#pragma unroll
            for (int r = 0; r < 4; ++r)
                part[w][m * 16 + half * 4 + r][n * 16 + q] = acc[m][n][r];
    __syncthreads();
    // reduce 8 K-slices: 2048 outputs, 4 per thread
    float gv[4];
#pragma unroll
    for (int k = 0; k < 4; ++k) {
        int o = tid + k * 512;
        int bb = o >> 5, x = o & 31;
        float v = 0.f;
#pragma unroll
        for (int w2 = 0; w2 < 8; ++w2) v += part[w2][bb][x];
        int gr = (x >> 3) * 1024 + c0 + (x & 7);
        if (preG) v += bf2f(preG[(size_t)bb * 4096 + gr]);
        else      v += bia[gr] + bib[gr];
        gv[k] = v;
    }
    __syncthreads();
#pragma unroll
    for (int k = 0; k < 4; ++k) {
        int o = tid + k * 512;
        part[0][o >> 5][o & 31] = gv[k];
    }
    __syncthreads();
    // cell: 512 threads, one (b, col) each
    int bb = tid >> 3, j = tid & 7, ccol = c0 + j;
    float ig = part[0][bb][j],      fg = part[0][bb][8 + j];
    float gg = part[0][bb][16 + j], og = part[0][bb][24 + j];
    float cp = cbuf[bb * 1024 + ccol];
    float cnew = sigm(fg) * cp + sigm(ig) * tanhf(gg);
    float hnew = sigm(og) * tanhf(cnew);
    cbuf[bb * 1024 + ccol] = cnew;
    u16 hb16 = f2bf(hnew);
    hA[bb * 2048 + ccol] = hb16;
    if (hB) hB[bb * 2048 + ccol] = hb16;
    if (outBase) outBase[((size_t)bb * T_ + t) * H_ + ccol] = hnew;
    if (last) { hnOut[bb * 1024 + ccol] = hnew; cnOut[bb * 1024 + ccol] = cnew; }
}

// ---------------------------------------------------------------------------

extern "C" void kernel_launch(void* const* d_in, const int* in_sizes, int n_in,
                              void* d_out, int out_size, void* d_ws, size_t ws_size,
                              hipStream_t stream) {
    const int*   tgt      = (const int*)d_in[0];
    const float* h0       = (const float*)d_in[1];
    const float* c0in     = (const float*)d_in[2];
    const float* enc      = (const float*)d_in[3];
    const unsigned char* mask = (const unsigned char*)d_in[4];
    const float* embedding= (const float*)d_in[5];
    const float* W_l      = (const float*)d_in[6];
    const float* b_l      = (const float*)d_in[7];
    const float* W_ih0    = (const float*)d_in[8];
    const float* W_hh0    = (const float*)d_in[9];
    const float* b_ih0    = (const float*)d_in[10];
    const float* b_hh0    = (const float*)d_in[11];
    const float* W_ih1    = (const float*)d_in[12];
    const float* W_hh1    = (const float*)d_in[13];
    const float* b_ih1    = (const float*)d_in[14];
    const float* b_hh1    = (const float*)d_in[15];
    float* out = (float*)d_out;

    char* ws = (char*)d_ws;
    u16* W0emb = (u16*)ws;               ws += (size_t)4096 * 512 * 2;
    u16* W0cat = (u16*)ws;               ws += (size_t)4096 * 2048 * 2;
    u16* W1cat = (u16*)ws;               ws += (size_t)4096 * 2048 * 2;
    u16* WlT   = (u16*)ws;               ws += (size_t)1024 * 1024 * 2;
    u16* embA  = (u16*)ws;               ws += (size_t)3072 * 512 * 2;
    u16* encB  = (u16*)ws;               ws += (size_t)3072 * 1024 * 2;
    u16* encWb = (u16*)ws;               ws += (size_t)3072 * 1024 * 2;
    float* sbias = (float*)ws;           ws += (size_t)3072 * 4;
    u16* preG  = (u16*)ws;               ws += (size_t)3072 * 4096 * 2;
    u16* XA0   = (u16*)ws;               ws += (size_t)2 * 64 * 2048 * 2;
    u16* XA1   = (u16*)ws;               ws += (size_t)2 * 64 * 2048 * 2;
    float* c0buf = (float*)ws;           ws += (size_t)64 * 1024 * 4;
    float* c1buf = (float*)ws;           ws += (size_t)64 * 1024 * 4;

    // ---- one-time (per launch) setup ----
    cast_copy<<<2048, 256, 0, stream>>>(W0emb, 512, 0,    W_ih0, 1536, 0,   4096, 9);
    cast_copy<<<2048, 256, 0, stream>>>(W0cat, 2048, 0,   W_ih0, 1536, 512, 4096, 10);
    cast_copy<<<2048, 256, 0, stream>>>(W0cat, 2048, 1024, W_hh0, 1024, 0,  4096, 10);
    cast_copy<<<2048, 256, 0, stream>>>(W1cat, 2048, 0,   W_ih1, 1024, 0,   4096, 10);
    cast_copy<<<2048, 256, 0, stream>>>(W1cat, 2048, 1024, W_hh1, 1024, 0,  4096, 10);
    cast_copy<<<2048, 256, 0, stream>>>(encB, 1024, 0,    enc,   1024, 0,   3072, 10);
    transpose_cast<<<4096, 256, 0, stream>>>(WlT, W_l);
    embed_gather<<<3072, 256, 0, stream>>>(embA, embedding, tgt);
    init_state<<<512, 256, 0, stream>>>(XA0, XA1, c0buf, c1buf, h0, c0in);
    sbias_kernel<<<3072, 64, 0, stream>>>(sbias, enc, b_l);
    // preG = embA @ W0emb^T + b_ih0 + b_hh0   (M=3072, N=4096, K=512)
    gemm64<<<dim3(64, 48), 256, 0, stream>>>(embA, W0emb, preG, b_ih0, b_hh0, 4096, 512);
    // encW = encB @ W_l                        (M=3072, N=1024, K=1024)
    gemm64<<<dim3(16, 48), 256, 0, stream>>>(encB, WlT, encWb, nullptr, nullptr, 1024, 1024);

    float* hn0 = out + 3145728;           // hn[0]
    float* hn1 = hn0 + 65536;             // hn[1]
    float* cn0 = out + 3276800;           // cn[0]
    float* cn1 = cn0 + 65536;             // cn[1]

    for (int t = 0; t < T_; ++t) {
        int p = t & 1, pn = p ^ 1, last = (t == T_ - 1);
        u16* xa0c = XA0 + (size_t)p  * 131072;
        u16* xa0n = XA0 + (size_t)pn * 131072;
        u16* xa1c = XA1 + (size_t)p  * 131072;
        u16* xa1n = XA1 + (size_t)pn * 131072;

        // attention: ctx -> XA0cur[:, 0:1024]
        attn_kernel<<<64, 256, 0, stream>>>(xa1c, encWb, encB, sbias, mask, xa0c);
        // layer 0: gates from [ctx|h0] + preG, cell -> h0' (XA1cur[:,0:1024],
        // XA0next[:,1024:2048]); c0buf updated
        lstm_fused<<<128, 512, 0, stream>>>(
            xa0c, W0cat, preG + (size_t)t * 64 * 4096, nullptr, nullptr,
            c0buf, xa1c, xa0n + 1024, nullptr, t, last, hn0, cn0);
        // layer 1: gates from [h0'|h1] + biases, cell -> h1'
        // (XA1next[:,1024:2048]) + outputs[b][t][:]
        lstm_fused<<<128, 512, 0, stream>>>(
            xa1c, W1cat, nullptr, b_ih1, b_hh1,
            c1buf, xa1n + 1024, nullptr, out, t, last, hn1, cn1);
    }
    (void)in_sizes; (void)n_in; (void)out_size; (void)ws_size; (void)mask;
}